// Round 6
// baseline (211.658 us; speedup 1.0000x reference)
//
#include <hip/hip_runtime.h>
#include <math.h>

// ---- static config (mirrors reference) ----
#define BB 16
#define AA 3
#define NCC 80
#define WW 76
#define MM 32
#define CELLS_PER_IMG (AA * WW * WW)          // 17328
#define NDECODE (BB * CELLS_PER_IMG * 85)     // 23,566,080
#define NCELLS (BB * CELLS_PER_IMG)           // 277,248

// 24 cells * 85 = 2040 floats = 510 float4 exactly; 24 | 17328 so a block
// never crosses an image boundary. 277248/24 = 11552 blocks (= 722*16).
#define CPB 24
#define V4PB 510

typedef float vfloat4 __attribute__((ext_vector_type(4)));

__constant__ float c_anchor[9][2] = {
    {10.f,13.f},{16.f,30.f},{33.f,23.f},{30.f,61.f},{62.f,45.f},
    {59.f,119.f},{116.f,90.f},{156.f,198.f},{373.f,326.f}};

#define LOG2E 1.4426950408889634f

__device__ __forceinline__ float fast_sigmoid(float x) {
    return __builtin_amdgcn_rcpf(1.0f + __builtin_amdgcn_exp2f(-x * LOG2E));
}

// ---------------------------------------------------------------------------
// Fused kernel: each 256-thread block owns 24 whole cells of one image.
// Phase 1: branchless streaming sigmoid of the block's 510 float4s (the 4 box
//   channels per cell get a wrong value here, fixed in phase 2).
// Phase 2 (threads 0..23): decode box channels from raw input (L1-hot),
//   overwrite the 4 box slots in dec, max-IoU vs 32 LDS-staged GT -> noobj,
//   zero obj. __syncthreads() orders phase-2 stores after phase-1 stores.
// ---------------------------------------------------------------------------
__global__ void fused_decode_noobj_kernel(const float* __restrict__ pred,
                                          const float* __restrict__ gt,
                                          float* __restrict__ dec,
                                          float* __restrict__ noobj,
                                          float* __restrict__ obj) {
    __shared__ float4 sbox[MM];
    const int blk = blockIdx.x;
    const int t = threadIdx.x;
    const int b = blk / 722;                 // image index (722 blocks/image)
    const int n0 = (blk - b * 722) * CPB;    // first in-image cell index
    const size_t cell0 = (size_t)b * CELLS_PER_IMG + n0;

    if (t < MM) {
        const float* g = gt + (size_t)(b * MM + t) * 6;
        float cx = g[1], cy = g[2], gw = g[3], gh = g[4];
        sbox[t] = make_float4((cx - gw * 0.5f) * 608.0f, (cy - gh * 0.5f) * 608.0f,
                              (cx + gw * 0.5f) * 608.0f, (cy + gh * 0.5f) * 608.0f);
    }

    // ---- phase 1: bulk sigmoid over this block's 510 float4s ----
    const vfloat4* in4 = (const vfloat4*)pred + cell0 * 85 / 4;
    vfloat4* out4 = (vfloat4*)dec + cell0 * 85 / 4;
    {
        vfloat4 v = in4[t];
        vfloat4 o;
        o.x = fast_sigmoid(v.x); o.y = fast_sigmoid(v.y);
        o.z = fast_sigmoid(v.z); o.w = fast_sigmoid(v.w);
        out4[t] = o;
        int i1 = t + 256;
        if (i1 < V4PB) {
            vfloat4 v2 = in4[i1];
            vfloat4 o2;
            o2.x = fast_sigmoid(v2.x); o2.y = fast_sigmoid(v2.y);
            o2.z = fast_sigmoid(v2.z); o2.w = fast_sigmoid(v2.w);
            out4[i1] = o2;
        }
    }
    __syncthreads();   // order phase-2 box overwrites after phase-1 stores; sbox ready

    // ---- phase 2: box fixup + noobj for the block's 24 cells ----
    if (t >= CPB) return;
    int n = n0 + t;
    size_t cell = cell0 + t;
    const float* ip = pred + cell * 85;
    int h = n % WW;
    int w = (n / WW) % WW;
    int a = n / (WW * WW);                   // n < 3*76*76
    float px = fast_sigmoid(ip[0]) + (float)h;
    float py = fast_sigmoid(ip[1]) + (float)w;
    float pw = __builtin_amdgcn_exp2f(ip[2] * LOG2E) * (c_anchor[a][0] * 0.125f);
    float ph = __builtin_amdgcn_exp2f(ip[3] * LOG2E) * (c_anchor[a][1] * 0.125f);
    float* op = dec + cell * 85;
    op[0] = px; op[1] = py; op[2] = pw; op[3] = ph;

    // replicate reference FP order: (val)/W * INPUTW
    float x1 = (px - pw * 0.5f) / 76.0f * 608.0f;
    float y1 = (py - ph * 0.5f) / 76.0f * 608.0f;
    float x2 = (px + pw * 0.5f) / 76.0f * 608.0f;
    float y2 = (py + ph * 0.5f) / 76.0f * 608.0f;
    float area2 = (x2 - x1) * (y2 - y1);
    float best = 0.0f;   // iou >= 0 always
#pragma unroll
    for (int m = 0; m < MM; ++m) {
        float4 gb = sbox[m];
        float area1 = (gb.z - gb.x) * (gb.w - gb.y);
        float ltx = fmaxf(gb.x, x1), lty = fmaxf(gb.y, y1);
        float rbx = fminf(gb.z, x2), rby = fminf(gb.w, y2);
        float inter = fmaxf(rbx - ltx, 0.0f) * fmaxf(rby - lty, 0.0f);
        float iou = inter * __builtin_amdgcn_rcpf(area1 + area2 - inter);
        best = fmaxf(best, iou);
    }
    noobj[cell] = (best <= 0.5f) ? 1.0f : 0.0f;
    obj[cell] = 0.0f;
}

// ---------------------------------------------------------------------------
// Per-GT best-anchor argmax (first-max tiebreak, exact fdiv preserves argmax
// ordering). Idempotent constant scatter -> no atomics. Must run after the
// fused kernel (stream order) since it overwrites noobj/obj at hit cells.
// ---------------------------------------------------------------------------
__global__ void assign_kernel(const float* __restrict__ gt,
                              float* __restrict__ noobj, float* __restrict__ obj) {
    int r = blockIdx.x * blockDim.x + threadIdx.x;
    if (r >= BB * MM) return;
    const float* g = gt + (size_t)r * 6;
    float cx = g[1], cy = g[2], gw = g[3], gh = g[4];
    float gx1 = (cx - gw * 0.5f) * 608.0f, gy1 = (cy - gh * 0.5f) * 608.0f;
    float gx2 = (cx + gw * 0.5f) * 608.0f, gy2 = (cy + gh * 0.5f) * 608.0f;
    float area_g = (gx2 - gx1) * (gy2 - gy1);
    int best = 0;
    float bestv = -1.0f;
#pragma unroll
    for (int k = 0; k < 9; ++k) {
        float ow = c_anchor[k][0] / 608.0f, oh = c_anchor[k][1] / 608.0f;
        float ax1 = (cx - ow * 0.5f) * 608.0f, ay1 = (cy - oh * 0.5f) * 608.0f;
        float ax2 = (cx + ow * 0.5f) * 608.0f, ay2 = (cy + oh * 0.5f) * 608.0f;
        float ltx = fmaxf(gx1, ax1), lty = fmaxf(gy1, ay1);
        float rbx = fminf(gx2, ax2), rby = fminf(gy2, ay2);
        float inter = fmaxf(rbx - ltx, 0.0f) * fmaxf(rby - lty, 0.0f);
        float area_a = (ax2 - ax1) * (ay2 - ay1);
        float v = inter / (area_g + area_a - inter);
        if (v > bestv) { bestv = v; best = k; }
    }
    if (best < AA) {
        int b = r / MM;  // reference uses row position, not the gt batch column
        int gi = (int)(cx * 76.0f);
        int gj = (int)(cy * 76.0f);
        int flat = ((b * AA + best) * WW + gi) * WW + gj;
        obj[flat] = 1.0f;
        noobj[flat] = 0.0f;
    }
}

extern "C" void kernel_launch(void* const* d_in, const int* in_sizes, int n_in,
                              void* d_out, int out_size, void* d_ws, size_t ws_size,
                              hipStream_t stream) {
    const float* pred = (const float*)d_in[0];
    const float* gt   = (const float*)d_in[1];
    float* dec   = (float*)d_out;            // 23,566,080
    float* noobj = dec + NDECODE;            //    277,248
    float* obj   = noobj + NCELLS;           //    277,248

    fused_decode_noobj_kernel<<<NCELLS / CPB, 256, 0, stream>>>(pred, gt, dec, noobj, obj);
    assign_kernel<<<2, 256, 0, stream>>>(gt, noobj, obj);
}

// Round 7
// 200.350 us; speedup vs baseline: 1.0564x; 1.0564x over previous
//
#include <hip/hip_runtime.h>
#include <math.h>

// ---- static config (mirrors reference) ----
#define BB 16
#define AA 3
#define NCC 80
#define WW 76
#define MM 32
#define CELLS_PER_IMG (AA * WW * WW)          // 17328
#define NDECODE (BB * CELLS_PER_IMG * 85)     // 23,566,080
#define NCELLS (BB * CELLS_PER_IMG)           // 277,248

typedef float vfloat4 __attribute__((ext_vector_type(4)));

__constant__ float c_anchor[9][2] = {
    {10.f,13.f},{16.f,30.f},{33.f,23.f},{30.f,61.f},{62.f,45.f},
    {59.f,119.f},{116.f,90.f},{156.f,198.f},{373.f,326.f}};

#define LOG2E 1.4426950408889634f

__device__ __forceinline__ float fast_sigmoid(float x) {
    return __builtin_amdgcn_rcpf(1.0f + __builtin_amdgcn_exp2f(-x * LOG2E));
}

// ---------------------------------------------------------------------------
// Kernel 1: decode. One %85 per thread. Fast path (4 <= r <= 81, ~92% of
// threads): pure sigmoid4, no integer work. Slow path (~6 lanes/wave):
// per-element decode writing CORRECT box values into dec AND a compact
// boxes[NCELLS][4] scratch. No later RMW into dec (R6 lesson: partial-line
// overwrites cost +34MB HBM); no barrier fusion (R6 lesson: kills MLP).
// ---------------------------------------------------------------------------
__global__ void decode_kernel(const vfloat4* __restrict__ in, vfloat4* __restrict__ out,
                              float* __restrict__ boxes) {
    const int n4 = NDECODE / 4;
    int tid = blockIdx.x * blockDim.x + threadIdx.x;
    if (tid >= n4) return;
    vfloat4 v = in[tid];
    vfloat4 o;
    o.x = fast_sigmoid(v.x);
    o.y = fast_sigmoid(v.y);
    o.z = fast_sigmoid(v.z);
    o.w = fast_sigmoid(v.w);

    int base = tid * 4;
    int cell0 = base / 85;               // one magic-mul chain per thread
    int r = base - cell0 * 85;
    if (r < 4 || r > 81) {               // this float4 touches box channels
        float vals[4] = {v.x, v.y, v.z, v.w};
        float res[4] = {o.x, o.y, o.z, o.w};
        int c = r, cell = cell0;
#pragma unroll
        for (int j = 0; j < 4; ++j) {
            if (c < 4) {
                float rr;
                if (c < 2) {
                    // n within image: cell%76 == n%76 and (cell/76)%76 == (n/76)%76
                    // because 17328 = 76*228 and 228 = 76*3.
                    int q = (c == 0) ? (cell % WW) : ((cell / WW) % WW);
                    rr = fast_sigmoid(vals[j]) + (float)q;
                } else {
                    int a = (cell / (WW * WW)) % AA;
                    float an = (c == 2) ? c_anchor[a][0] : c_anchor[a][1];
                    rr = __builtin_amdgcn_exp2f(vals[j] * LOG2E) * (an * 0.125f);
                }
                res[j] = rr;
                boxes[cell * 4 + c] = rr;
            }
            if (++c == 85) { c = 0; ++cell; }
        }
        o.x = res[0]; o.y = res[1]; o.z = res[2]; o.w = res[3];
    }
    out[tid] = o;
}

// ---------------------------------------------------------------------------
// Kernel 2: per-cell max-IoU vs the image's 32 GT boxes -> noobj; zero obj.
// Reads the dense boxes buffer (coalesced float4). GT boxes staged in LDS.
// ---------------------------------------------------------------------------
__global__ void noobj_kernel(const float4* __restrict__ boxes, const float* __restrict__ gt,
                             float* __restrict__ noobj, float* __restrict__ obj) {
    __shared__ float4 sbox[MM];
    int b = blockIdx.y;
    int t = threadIdx.x;
    if (t < MM) {
        const float* g = gt + (size_t)(b * MM + t) * 6;
        float cx = g[1], cy = g[2], gw = g[3], gh = g[4];
        sbox[t] = make_float4((cx - gw * 0.5f) * 608.0f, (cy - gh * 0.5f) * 608.0f,
                              (cx + gw * 0.5f) * 608.0f, (cy + gh * 0.5f) * 608.0f);
    }
    __syncthreads();
    int n = blockIdx.x * blockDim.x + t;
    if (n >= CELLS_PER_IMG) return;
    size_t idx = (size_t)b * CELLS_PER_IMG + n;
    float4 pb = boxes[idx];
    float px = pb.x, py = pb.y, pw = pb.z, ph = pb.w;
    // replicate reference FP order: (val)/W * INPUTW
    float x1 = (px - pw * 0.5f) / 76.0f * 608.0f;
    float y1 = (py - ph * 0.5f) / 76.0f * 608.0f;
    float x2 = (px + pw * 0.5f) / 76.0f * 608.0f;
    float y2 = (py + ph * 0.5f) / 76.0f * 608.0f;
    float area2 = (x2 - x1) * (y2 - y1);
    float best = 0.0f;  // iou >= 0 always
#pragma unroll
    for (int m = 0; m < MM; ++m) {
        float4 gb = sbox[m];
        float area1 = (gb.z - gb.x) * (gb.w - gb.y);
        float ltx = fmaxf(gb.x, x1), lty = fmaxf(gb.y, y1);
        float rbx = fminf(gb.z, x2), rby = fminf(gb.w, y2);
        float inter = fmaxf(rbx - ltx, 0.0f) * fmaxf(rby - lty, 0.0f);
        float iou = inter * __builtin_amdgcn_rcpf(area1 + area2 - inter);
        best = fmaxf(best, iou);
    }
    noobj[idx] = (best <= 0.5f) ? 1.0f : 0.0f;
    obj[idx] = 0.0f;
}

// ---------------------------------------------------------------------------
// Kernel 3: per-GT best-anchor argmax (first-max tiebreak, exact fdiv keeps
// argmax ordering). Idempotent constant scatter -> no atomics. Runs after
// kernel 2 (stream order).
// ---------------------------------------------------------------------------
__global__ void assign_kernel(const float* __restrict__ gt,
                              float* __restrict__ noobj, float* __restrict__ obj) {
    int r = blockIdx.x * blockDim.x + threadIdx.x;
    if (r >= BB * MM) return;
    const float* g = gt + (size_t)r * 6;
    float cx = g[1], cy = g[2], gw = g[3], gh = g[4];
    float gx1 = (cx - gw * 0.5f) * 608.0f, gy1 = (cy - gh * 0.5f) * 608.0f;
    float gx2 = (cx + gw * 0.5f) * 608.0f, gy2 = (cy + gh * 0.5f) * 608.0f;
    float area_g = (gx2 - gx1) * (gy2 - gy1);
    int best = 0;
    float bestv = -1.0f;
#pragma unroll
    for (int k = 0; k < 9; ++k) {
        float ow = c_anchor[k][0] / 608.0f, oh = c_anchor[k][1] / 608.0f;
        float ax1 = (cx - ow * 0.5f) * 608.0f, ay1 = (cy - oh * 0.5f) * 608.0f;
        float ax2 = (cx + ow * 0.5f) * 608.0f, ay2 = (cy + oh * 0.5f) * 608.0f;
        float ltx = fmaxf(gx1, ax1), lty = fmaxf(gy1, ay1);
        float rbx = fminf(gx2, ax2), rby = fminf(gy2, ay2);
        float inter = fmaxf(rbx - ltx, 0.0f) * fmaxf(rby - lty, 0.0f);
        float area_a = (ax2 - ax1) * (ay2 - ay1);
        float v = inter / (area_g + area_a - inter);
        if (v > bestv) { bestv = v; best = k; }
    }
    if (best < AA) {
        int b = r / MM;  // reference uses row position, not the gt batch column
        int gi = (int)(cx * 76.0f);
        int gj = (int)(cy * 76.0f);
        int flat = ((b * AA + best) * WW + gi) * WW + gj;
        obj[flat] = 1.0f;
        noobj[flat] = 0.0f;
    }
}

extern "C" void kernel_launch(void* const* d_in, const int* in_sizes, int n_in,
                              void* d_out, int out_size, void* d_ws, size_t ws_size,
                              hipStream_t stream) {
    const float* pred = (const float*)d_in[0];
    const float* gt   = (const float*)d_in[1];
    float* dec   = (float*)d_out;            // 23,566,080
    float* noobj = dec + NDECODE;            //    277,248
    float* obj   = noobj + NCELLS;           //    277,248
    float* boxes = (float*)d_ws;             // NCELLS*4 floats = 4.4 MB scratch

    const int n4 = NDECODE / 4;              // 5,891,520
    decode_kernel<<<(n4 + 255) / 256, 256, 0, stream>>>(
        (const vfloat4*)pred, (vfloat4*)dec, boxes);

    dim3 gb((CELLS_PER_IMG + 255) / 256, BB);
    noobj_kernel<<<gb, 256, 0, stream>>>((const float4*)boxes, gt, noobj, obj);

    assign_kernel<<<2, 256, 0, stream>>>(gt, noobj, obj);
}